// Round 14
// baseline (2105.267 us; speedup 1.0000x reference)
//
#include <hip/hip_runtime.h>
#include <math.h>

// PnPNystra attention, MFMA v13 = v12 + 32x32-tile Newton-Schulz (phase D).
// Diagnosis: k_main is LDS-BW-bound (~160-220KB/phase through a 128B/cy pipe).
// 32x32 tiles read 16B/output-elem vs 32B for 16x16 -> D traffic ~1.55x lower.
// D: ph1 M=X@Z (waves 0-3, X reg-cached); ph2 {P=M@M w0-3, Ws=Zs@M w4-7},
//    OP=7M-P from regs -> X planes (scratch; X lives in regs);
//    ph3 Ys=Ws@OP + Znew=0.25(13Zs-15Ws+Ys) elementwise from regs (w4-7).
// E/B/F unchanged from v12 (16x16, pipelined F, MFMA kv1/den).
// Numerics: split f16 (v ~= h + l/2048), 3x mfma, Z scaled 1024.

#define G_TOT 4096
#define TPB_R 256
#define TPB_M 1024
typedef _Float16 f16;
typedef __attribute__((ext_vector_type(2))) _Float16 f16x2;
typedef __attribute__((ext_vector_type(4))) _Float16 f16x4;
typedef __attribute__((ext_vector_type(8))) _Float16 f16x8;
typedef __attribute__((ext_vector_type(4))) float f32x4;
typedef __attribute__((ext_vector_type(16))) float f32x16;

#define NPLANES 16
#define SMEM_BYTES (NPLANES * 4096 * 2 + 256)

#define LSCALE 2048.0f
#define LINV   (1.0f / 2048.0f)
#define ZS     1024.0f
#define ZINV   (1.0f / 1024.0f)

struct HL { f16 h, l; };
__device__ __forceinline__ HL split2(float v) {
    HL r;
    r.h = (f16)v;
    r.l = (f16)((v - (float)r.h) * LSCALE);
    return r;
}
__device__ __forceinline__ float join2(f16 h, f16 l) {
    return (float)h + (float)l * LINV;
}
__device__ __forceinline__ int swi(int r, int c) {
    return (r << 6) + (c ^ ((r & 7) << 3));
}
__device__ __forceinline__ float activ_f(float x) {
    return __expf(fminf(x, 5.0f)) + fmaxf(x - 5.0f, 0.0f);
}
__device__ __forceinline__ float activ_r(float x) {
    return expf(fminf(x, 5.0f)) + fmaxf(x - 5.0f, 0.0f);
}
__device__ __forceinline__ void split_w(f16* Ph, f16* Pl, int r, int c, float v) {
    HL s = split2(v);
    const int o = swi(r, c);
    Ph[o] = s.h;
    Pl[o] = s.l;
}
__device__ __forceinline__ f16x2 mk2(f16 a, f16 b) { f16x2 r; r[0]=a; r[1]=b; return r; }
__device__ __forceinline__ f16x4 mk4(f16 a, f16 b, f16 c, f16 d) { f16x4 r; r[0]=a;r[1]=b;r[2]=c;r[3]=d; return r; }
__device__ __forceinline__ f32x4 z4() { f32x4 z = {0.f,0.f,0.f,0.f}; return z; }
__device__ __forceinline__ f32x16 z16() {
    f32x16 z;
#pragma unroll
    for (int i = 0; i < 16; ++i) z[i] = 0.f;
    return z;
}

struct Frag { f16x8 h[2], l[2]; };
struct Frag32 { f16x8 h, l; };

__device__ __forceinline__ Frag ld_frag(const f16* __restrict__ Ph,
                                        const f16* __restrict__ Pl,
                                        int row, int kg) {
    Frag f;
    const int base = row << 6, x = (row & 7) << 3;
#pragma unroll
    for (int s = 0; s < 2; ++s) {
        const int o = base + ((((s << 5) + (kg << 3))) ^ x);
        f.h[s] = *(const f16x8*)(Ph + o);
        f.l[s] = *(const f16x8*)(Pl + o);
    }
    return f;
}

// 32x32 operand: row = rowbase + (lane&31), k = ks*16 + (lane>>5)*8 .. +8
__device__ __forceinline__ Frag32 ld_frag32(const f16* __restrict__ Ph,
                                            const f16* __restrict__ Pl,
                                            int rowbase, int lane, int ks) {
    const int r = rowbase + (lane & 31);
    const int k0 = (ks << 4) + ((lane >> 5) << 3);
    const int o = (r << 6) + (k0 ^ ((r & 7) << 3));
    Frag32 f;
    f.h = *(const f16x8*)(Ph + o);
    f.l = *(const f16x8*)(Pl + o);
    return f;
}

// 16x16 3-term split matmul, 2 accumulator chains
__device__ __forceinline__ f32x4 mm16_rr(const Frag& A, const Frag& B, f32x4 acc) {
    f32x4 ax = z4();
#pragma unroll
    for (int s = 0; s < 2; ++s) {
        acc = __builtin_amdgcn_mfma_f32_16x16x32_f16(A.h[s], B.h[s], acc, 0, 0, 0);
        ax  = __builtin_amdgcn_mfma_f32_16x16x32_f16(A.h[s], B.l[s], ax, 0, 0, 0);
        ax  = __builtin_amdgcn_mfma_f32_16x16x32_f16(A.l[s], B.h[s], ax, 0, 0, 0);
    }
    acc += ax * LINV;
    return acc;
}

// 32x32 3-term split matmul over K=64 (4 k-steps), LDS A and B
__device__ __forceinline__ f32x16 mm32(const f16* __restrict__ Ah, const f16* __restrict__ Al, int arb,
                                       const f16* __restrict__ Bh, const f16* __restrict__ Bl, int brb,
                                       int lane, f32x16 acc) {
    f32x16 ax = z16();
#pragma unroll
    for (int ks = 0; ks < 4; ++ks) {
        Frag32 A = ld_frag32(Ah, Al, arb, lane, ks);
        Frag32 B = ld_frag32(Bh, Bl, brb, lane, ks);
        acc = __builtin_amdgcn_mfma_f32_32x32x16_f16(A.h, B.h, acc, 0, 0, 0);
        ax  = __builtin_amdgcn_mfma_f32_32x32x16_f16(A.h, B.l, ax, 0, 0, 0);
        ax  = __builtin_amdgcn_mfma_f32_32x32x16_f16(A.l, B.h, ax, 0, 0, 0);
    }
    acc += ax * LINV;
    return acc;
}
// same, A cached in registers
__device__ __forceinline__ f32x16 mm32_ca(const Frag32* __restrict__ Af,
                                          const f16* __restrict__ Bh, const f16* __restrict__ Bl, int brb,
                                          int lane, f32x16 acc) {
    f32x16 ax = z16();
#pragma unroll
    for (int ks = 0; ks < 4; ++ks) {
        Frag32 B = ld_frag32(Bh, Bl, brb, lane, ks);
        acc = __builtin_amdgcn_mfma_f32_32x32x16_f16(Af[ks].h, B.h, acc, 0, 0, 0);
        ax  = __builtin_amdgcn_mfma_f32_32x32x16_f16(Af[ks].h, B.l, ax, 0, 0, 0);
        ax  = __builtin_amdgcn_mfma_f32_32x32x16_f16(Af[ks].l, B.h, ax, 0, 0, 0);
    }
    acc += ax * LINV;
    return acc;
}

__device__ __forceinline__ void wfrag_rm(f16* Ph, f16* Pl, int Rb, int C, const float* v) {
#pragma unroll
    for (int m = 0; m < 4; ++m) split_w(Ph, Pl, Rb + m, C, v[m]);
}
__device__ __forceinline__ void wfrag_t(f16* Ph, f16* Pl, int Rb, int C, const float* v) {
    const int o = swi(C, Rb);
    HL s0 = split2(v[0]), s1 = split2(v[1]), s2 = split2(v[2]), s3 = split2(v[3]);
    *(f16x4*)(Ph + o) = mk4(s0.h, s1.h, s2.h, s3.h);
    *(f16x4*)(Pl + o) = mk4(s0.l, s1.l, s2.l, s3.l);
}
// 32x32 C-layout writes: R = rb + (m&3) + 8*(m>>2) + 4*(lane>>5), C = cb + (lane&31)
__device__ __forceinline__ void wfrag32_rm(f16* Ph, f16* Pl, int rb, int cb, int lane, const float* v) {
    const int C = cb + (lane & 31), hh4 = ((lane >> 5) << 2);
#pragma unroll
    for (int m = 0; m < 16; ++m) {
        const int R = rb + (m & 3) + ((m >> 2) << 3) + hh4;
        split_w(Ph, Pl, R, C, v[m]);
    }
}
__device__ __forceinline__ void wfrag32_t(f16* Ph, f16* Pl, int rb, int cb, int lane, const float* v) {
    const int C = cb + (lane & 31), hh4 = ((lane >> 5) << 2);
#pragma unroll
    for (int g = 0; g < 4; ++g) {
        const int R0 = rb + (g << 3) + hh4;
        const int o = swi(C, R0);
        HL s0 = split2(v[(g << 2)]), s1 = split2(v[(g << 2) + 1]);
        HL s2 = split2(v[(g << 2) + 2]), s3 = split2(v[(g << 2) + 3]);
        *(f16x4*)(Ph + o) = mk4(s0.h, s1.h, s2.h, s3.h);
        *(f16x4*)(Pl + o) = mk4(s0.l, s1.l, s2.l, s3.l);
    }
}

// ---- staging helpers (1024 threads) ----
__device__ __forceinline__ void wr_rm(float4 vv, f16* Ph, f16* Pl, int t) {
    const int r = t >> 4, c4 = (t & 15) << 2;
    const int o = swi(r, c4);
    HL s0 = split2(vv.x), s1 = split2(vv.y), s2 = split2(vv.z), s3 = split2(vv.w);
    *(f16x4*)(Ph + o) = mk4(s0.h, s1.h, s2.h, s3.h);
    *(f16x4*)(Pl + o) = mk4(s0.l, s1.l, s2.l, s3.l);
}
__device__ __forceinline__ void ld_vt(const float* __restrict__ src, int t,
                                      float2& va, float2& vb) {
    const int n0 = (t >> 5) << 1, e0 = (t & 31) << 1;
    va = *(const float2*)(src + (size_t)n0 * 64 + e0);
    vb = *(const float2*)(src + (size_t)(n0 + 1) * 64 + e0);
}
__device__ __forceinline__ void wr_vt(float2 va, float2 vb, f16* Ph, f16* Pl, int t) {
    const int n0 = (t >> 5) << 1, e0 = (t & 31) << 1;
    HL ax = split2(va.x), ay = split2(va.y), bx = split2(vb.x), by = split2(vb.y);
    const int o0 = swi(e0, n0), o1 = swi(e0 + 1, n0);
    *(f16x2*)(Ph + o0) = mk2(ax.h, bx.h);
    *(f16x2*)(Pl + o0) = mk2(ax.l, bx.l);
    *(f16x2*)(Ph + o1) = mk2(ay.h, by.h);
    *(f16x2*)(Pl + o1) = mk2(ay.l, by.l);
}
__device__ __forceinline__ void pool_global1024(const float* __restrict__ src,
                                                f16* Ph, f16* Pl, int t) {
    const int L = t >> 4, d0 = (t & 15) << 2;
    const int nb = ((L >> 3) << 5) + ((L & 7) << 1);
    const float* p = src + (size_t)nb * 64 + d0;
    float4 a = *(const float4*)p;
    float4 b = *(const float4*)(p + 64);
    float4 c = *(const float4*)(p + 1024);
    float4 d = *(const float4*)(p + 1088);
    HL s0 = split2(0.25f * (a.x + b.x + c.x + d.x));
    HL s1 = split2(0.25f * (a.y + b.y + c.y + d.y));
    HL s2 = split2(0.25f * (a.z + b.z + c.z + d.z));
    HL s3 = split2(0.25f * (a.w + b.w + c.w + d.w));
    const int o = swi(L, d0);
    *(f16x4*)(Ph + o) = mk4(s0.h, s1.h, s2.h, s3.h);
    *(f16x4*)(Pl + o) = mk4(s0.l, s1.l, s2.l, s3.l);
}
__device__ __forceinline__ void pool_lds512(const f16* Kh, const f16* Kl,
                                            f16* Ph, f16* Pl, int t, int tt) {
    const int ll = t >> 5, d0 = (t & 31) << 1;
    const int rb = ((ll >> 3) << 5) + ((ll & 7) << 1);
    float s0 = 0.f, s1 = 0.f;
#pragma unroll
    for (int rr = 0; rr < 4; ++rr) {
        const int r = rb + (rr & 1) + ((rr >> 1) << 4);
        const int o = swi(r, d0);
        f16x2 h = *(const f16x2*)(Kh + o);
        f16x2 l = *(const f16x2*)(Kl + o);
        s0 += join2(h[0], l[0]);
        s1 += join2(h[1], l[1]);
    }
    const int L = (tt << 4) + ll;
    HL p0 = split2(0.25f * s0), p1 = split2(0.25f * s1);
    const int o = swi(L, d0);
    *(f16x2*)(Ph + o) = mk2(p0.h, p1.h);
    *(f16x2*)(Pl + o) = mk2(p0.l, p1.l);
}

// ---- k_reduce helpers (unchanged) ----
__device__ __forceinline__ f32x16 mm64q(const f16* __restrict__ Ah, const f16* __restrict__ Al,
                                        const f16* __restrict__ Bh, const f16* __restrict__ Bl,
                                        int lane, int wr, int wc, f32x16 acc) {
    const int cl = lane & 31, hh = lane >> 5;
    const int ar = (wr << 5) + cl, br = (wc << 5) + cl;
    const int abase = ar << 6, axor = (ar & 7) << 3;
    const int bbase = br << 6, bxor = (br & 7) << 3;
    f32x16 ax1 = z16();
    f32x16 ax2 = z16();
#pragma unroll
    for (int ks = 0; ks < 4; ++ks) {
        const int k0 = (ks << 4) + (hh << 3);
        const int ao = abase + (k0 ^ axor);
        const int bo = bbase + (k0 ^ bxor);
        f16x8 a_h = *(const f16x8*)(Ah + ao);
        f16x8 a_l = *(const f16x8*)(Al + ao);
        f16x8 b_h = *(const f16x8*)(Bh + bo);
        f16x8 b_l = *(const f16x8*)(Bl + bo);
        acc = __builtin_amdgcn_mfma_f32_32x32x16_f16(a_h, b_h, acc, 0, 0, 0);
        ax1 = __builtin_amdgcn_mfma_f32_32x32x16_f16(a_h, b_l, ax1, 0, 0, 0);
        ax2 = __builtin_amdgcn_mfma_f32_32x32x16_f16(a_l, b_h, ax2, 0, 0, 0);
    }
    acc += (ax1 + ax2) * LINV;
    return acc;
}
__device__ __forceinline__ void pool_global_r(const float* __restrict__ src,
                                              f16* Ph, f16* Pl, int t) {
    const int ll = t >> 4, d0 = (t & 15) << 2;
    const int rb = ((ll >> 3) << 5) + ((ll & 7) << 1);
#pragma unroll
    for (int tt = 0; tt < 4; ++tt) {
        const float* p = src + (size_t)((tt << 6) + rb) * 64 + d0;
        float4 a = *(const float4*)p;
        float4 b = *(const float4*)(p + 64);
        float4 c = *(const float4*)(p + 1024);
        float4 d = *(const float4*)(p + 1088);
        const int L = (tt << 4) + ll;
        split_w(Ph, Pl, L, d0 + 0, 0.25f * (a.x + b.x + c.x + d.x));
        split_w(Ph, Pl, L, d0 + 1, 0.25f * (a.y + b.y + c.y + d.y));
        split_w(Ph, Pl, L, d0 + 2, 0.25f * (a.z + b.z + c.z + d.z));
        split_w(Ph, Pl, L, d0 + 3, 0.25f * (a.w + b.w + c.w + d.w));
    }
}

#define WAVE_SUM32(v)            \
    v += __shfl_xor(v, 1);       \
    v += __shfl_xor(v, 2);       \
    v += __shfl_xor(v, 4);       \
    v += __shfl_xor(v, 8);       \
    v += __shfl_xor(v, 16);

__global__ void k_init(float* ws) {
    if (threadIdx.x < 2) ws[threadIdx.x] = 0.0f;
}

__global__ __launch_bounds__(TPB_R) void k_reduce(const float* __restrict__ q,
                                                  const float* __restrict__ k,
                                                  float* __restrict__ ws) {
    __shared__ f16 pls[4 * 4096];
    __shared__ float rowS[64], colS[64];
    const int t = threadIdx.x, g = blockIdx.x;
    const int lane = t & 63, wv = t >> 6, wr = wv >> 1, wc = wv & 1;
    const int cl = lane & 31, hh = lane >> 5;
    if (t < 64) rowS[t] = 0.f;
    else if (t < 128) colS[t - 64] = 0.f;
    pool_global_r(q + (size_t)g * 16384, pls, pls + 4096, t);
    pool_global_r(k + (size_t)g * 16384, pls + 8192, pls + 12288, t);
    __syncthreads();
    f32x16 a = mm64q(pls, pls + 4096, pls + 8192, pls + 12288, lane, wr, wc, z16());
    float colp = 0.f;
#pragma unroll
    for (int m = 0; m < 16; ++m) {
        float x = activ_r(a[m]);
        const int R = (wr << 5) + (m & 3) + ((m >> 2) << 3) + (hh << 2);
        float vs = x;
        WAVE_SUM32(vs)
        if (cl == 0) atomicAdd(&rowS[R], vs);
        colp += x;
    }
    colp += __shfl_xor(colp, 32);
    if (hh == 0) atomicAdd(&colS[(wc << 5) + cl], colp);
    __syncthreads();
    if (t < 64) {
        float vmx = rowS[t];
        for (int off = 1; off < 64; off <<= 1) vmx = fmaxf(vmx, __shfl_xor(vmx, off));
        if (t == 0) atomicMax((int*)ws, __float_as_int(vmx));
    } else if (t < 128) {
        float vmx = colS[t - 64];
        for (int off = 1; off < 64; off <<= 1) vmx = fmaxf(vmx, __shfl_xor(vmx, off));
        if (t == 64) atomicMax(((int*)ws) + 1, __float_as_int(vmx));
    }
}

// ============================ k_main (v13) ============================
__global__ __launch_bounds__(TPB_M, 4) void k_main(const float* __restrict__ q,
                                                   const float* __restrict__ k,
                                                   const float* __restrict__ v,
                                                   const float* __restrict__ ws,
                                                   float* __restrict__ out) {
    extern __shared__ f16 smu[];
    f16* kv1h = smu + NPLANES * 4096;
    f16* kv1l = kv1h + 64;
    const int t = threadIdx.x, g = blockIdx.x;
    const int lane = t & 63, w = t >> 6;
    const int ti = w & 3, tj = w >> 2;
    const int fr = lane & 15, kg = lane >> 4;
    const int arow = (ti << 4) + fr;
    const int brow = (tj << 4) + fr;
    const int C = brow;
    const int Rb = (ti << 4) + (kg << 2);
    const float* Gq = q + (size_t)g * 16384;
    const float* Gk = k + (size_t)g * 16384;
    const float* Gv = v + (size_t)g * 16384;
    float* og = out + (size_t)g * 16384;

    f16* Xh  = smu +  0 * 4096; f16* Xl  = smu +  1 * 4096;
    f16* SAh = smu +  2 * 4096; f16* SAl = smu +  3 * 4096;
    f16* SBh = smu +  4 * 4096; f16* SBl = smu +  5 * 4096;
    f16* KMh = smu +  6 * 4096; f16* KMl = smu +  7 * 4096;
    f16* SCh = smu +  8 * 4096; f16* SCl = smu +  9 * 4096;
    f16* KVh = smu + 10 * 4096; f16* KVl = smu + 11 * 4096;
    f16* Z0rh= smu + 12 * 4096; f16* Z0rl= smu + 13 * 4096;  // Zs row-major
    f16* Z0th= smu + 14 * 4096; f16* Z0tl= smu + 15 * 4096;  // Zs^T row-major

    Frag fOnes;
    {
        f16x8 one8, zer8;
#pragma unroll
        for (int i = 0; i < 8; ++i) { one8[i] = (f16)1.0f; zer8[i] = (f16)0.0f; }
        fOnes.h[0] = one8; fOnes.h[1] = one8;
        fOnes.l[0] = zer8; fOnes.l[1] = zer8;
    }

    // ---- prologue: pool QM -> Z0r planes; K0->SA, V0t->SB ----
    pool_global1024(Gq, Z0rh, Z0rl, t);
    {
        float4 kreg = *(const float4*)(Gk + (size_t)t * 4);
        float2 va, vb; ld_vt(Gv, t, va, vb);
        wr_rm(kreg, SAh, SAl, t);
        wr_vt(va, vb, SBh, SBl, t);
    }
    __syncthreads();

    Frag fQM = ld_frag(Z0rh, Z0rl, arow, kg);

    // ---- phase E: KV = activ(QM @ K^T) @ V ; pool KM ; kv1 via ones-MFMA ----
    f32x4 kva = z4();
    f32x4 kva1 = z4();
    for (int tt = 0; tt < 4; ++tt) {
        f16* vch = (tt & 1) ? Xh : SBh;  f16* vcl = (tt & 1) ? Xl : SBl;
        f16* vnh = (tt & 1) ? SBh : Xh;  f16* vnl = (tt & 1) ? SBl : Xl;
        float4 kregN; float2 vaN, vbN;
        if (tt < 3) {
            kregN = *(const float4*)(Gk + (size_t)(tt + 1) * 4096 + (size_t)t * 4);
            ld_vt(Gv + (size_t)(tt + 1) * 4096, t, vaN, vbN);
        }
        if (t < 512) pool_lds512(SAh, SAl, KMh, KMl, t, tt);
        {
            Frag bK = ld_frag(SAh, SAl, brow, kg);
            f32x4 s = mm16_rr(fQM, bK, z4());
            float sv[4];
#pragma unroll
            for (int m = 0; m < 4; ++m) sv[m] = activ_f(s[m]);
            wfrag_rm(SCh, SCl, Rb, C, sv);
        }
        if (tt < 3) wr_vt(vaN, vbN, vnh, vnl, t);
        __syncthreads();
        {
            Frag aS = ld_frag(SCh, SCl, arow, kg);
            Frag bV = ld_frag(vch, vcl, brow, kg);
            kva  = mm16_rr(aS, bV, kva);
            kva1 = mm16_rr(aS, fOnes, kva1);
        }
        if (tt < 3) wr_rm(kregN, SAh, SAl, t);
        __syncthreads();
    }

    // ---- phase B: KV store (T-layout); X = activ(QM@KM^T); Zs-init; kv1 split ----
    {
        float kvv[4] = {kva[0], kva[1], kva[2], kva[3]};
        wfrag_t(KVh, KVl, Rb, C, kvv);
        Frag fKMb = ld_frag(KMh, KMl, brow, kg);
        f32x4 x0 = mm16_rr(fQM, fKMb, z4());
        const float scale = ZS / (ws[0] * ws[1] + 1e-15f);
        float xv[4], zv[4];
#pragma unroll
        for (int m = 0; m < 4; ++m) { xv[m] = activ_f(x0[m]); zv[m] = xv[m] * scale; }
        wfrag_rm(Xh, Xl, Rb, C, xv);       // X rm
        wfrag_t (Z0rh, Z0rl, Rb, C, zv);   // Zs rm
        wfrag_rm(Z0th, Z0tl, Rb, C, zv);   // Zs^T rm
        if (tj == 0 && fr == 0) {
#pragma unroll
            for (int m = 0; m < 4; ++m) {
                HL s = split2(kva1[m]);
                kv1h[Rb + m] = s.h;
                kv1l[Rb + m] = s.l;
            }
        }
    }
    __syncthreads();

    // ---- phase D: 6 NS iterations, 32x32 tiles ----
    // waves 0-3: M (X reg-cached), P, OP ; waves 4-7: Ws, Ys, Znew (Zs/Ws in regs)
    const int idx2 = w & 3;
    const int rb32 = (idx2 >> 1) << 5;
    const int cb32 = (idx2 & 1) << 5;
    const int cl31 = lane & 31, hh4 = ((lane >> 5) << 2);
    Frag32 fX32[4];
    float zs[16], wvv[16], t1k32[16];
    if (w < 4) {
#pragma unroll
        for (int ks = 0; ks < 4; ++ks) fX32[ks] = ld_frag32(Xh, Xl, rb32, lane, ks);
    } else if (w < 8) {
#pragma unroll
        for (int m = 0; m < 16; ++m) {
            const int R = rb32 + (m & 3) + ((m >> 2) << 3) + hh4;
            const int o = swi(R, cb32 + cl31);
            zs[m] = join2(Z0rh[o], Z0rl[o]);
        }
    }
    for (int it = 0; it < 6; ++it) {
        // ph1: M = X @ Z  (waves 0-3; acc carries ZS)
        if (w < 4) {
            f32x16 a1 = mm32_ca(fX32, Z0th, Z0tl, cb32, lane, z16());
#pragma unroll
            for (int m = 0; m < 16; ++m) t1k32[m] = a1[m] * ZINV;
            wfrag32_rm(SAh, SAl, rb32, cb32, lane, t1k32);
            wfrag32_t (SCh, SCl, rb32, cb32, lane, t1k32);
        }
        __syncthreads();
        // ph2: P = M@M (w0-3) -> OP = 7M-P -> X planes (t-layout);
        //      Ws = Zs@M (w4-7) -> SB rm
        if (w < 4) {
            f32x16 pP = mm32(SAh, SAl, rb32, SCh, SCl, cb32, lane, z16());
            float opv[16];
#pragma unroll
            for (int m = 0; m < 16; ++m) opv[m] = 7.f * t1k32[m] - pP[m];
            wfrag32_t(Xh, Xl, rb32, cb32, lane, opv);
        } else if (w < 8) {
            f32x16 wS = mm32(Z0rh, Z0rl, rb32, SCh, SCl, cb32, lane, z16());
#pragma unroll
            for (int m = 0; m < 16; ++m) wvv[m] = wS[m];
            wfrag32_rm(SBh, SBl, rb32, cb32, lane, wvv);
        }
        __syncthreads();
        // ph3: Ys = Ws@OP ; Znew = 0.25(13 Zs - 15 Ws + Ys) (waves 4-7, regs)
        if (w >= 4 && w < 8) {
            f32x16 yS = mm32(SBh, SBl, rb32, Xh, Xl, cb32, lane, z16());
            float zk[16];
#pragma unroll
            for (int m = 0; m < 16; ++m) {
                zk[m] = 0.25f * (13.f * zs[m] - 15.f * wvv[m] + yS[m]);
                zs[m] = zk[m];
            }
            wfrag32_rm(Z0rh, Z0rl, rb32, cb32, lane, zk);
            wfrag32_t (Z0th, Z0tl, rb32, cb32, lane, zk);
        }
        __syncthreads();
    }
    // final: Zs rm in Z0r, Zs^T in Z0t

    // ---- phase F: pipelined — prod(t) || w(t+1) || qk(t+2), 6 barriers ----
    float4 qp0, qp1, qp2, qp3;
#define LOAD_Q(tt_)                                                              \
    {                                                                            \
        const float* rp = Gq + (size_t)(((tt_) << 6) + arow) * 64 + (kg << 3);   \
        qp0 = *(const float4*)(rp);      qp1 = *(const float4*)(rp + 4);         \
        qp2 = *(const float4*)(rp + 32); qp3 = *(const float4*)(rp + 36);        \
    }
#define BUILD_AQ(aQ_)                                                                          \
    {                                                                                          \
        HL s0 = split2(qp0.x), s1 = split2(qp0.y), s2 = split2(qp0.z), s3 = split2(qp0.w);     \
        HL s4 = split2(qp1.x), s5 = split2(qp1.y), s6 = split2(qp1.z), s7 = split2(qp1.w);     \
        f16x8 h, l;                                                                            \
        h[0]=s0.h; h[1]=s1.h; h[2]=s2.h; h[3]=s3.h; h[4]=s4.h; h[5]=s5.h; h[6]=s6.h; h[7]=s7.h;\
        l[0]=s0.l; l[1]=s1.l; l[2]=s2.l; l[3]=s3.l; l[4]=s4.l; l[5]=s5.l; l[6]=s6.l; l[7]=s7.l;\
        aQ_.h[0] = h; aQ_.l[0] = l;                                                            \
        HL t0 = split2(qp2.x), t1 = split2(qp2.y), t2 = split2(qp2.z), t3 = split2(qp2.w);     \
        HL t4 = split2(qp3.x), t5 = split2(qp3.y), t6 = split2(qp3.z), t7 = split2(qp3.w);     \
        f16x8 h2, l2;                                                                          \
        h2[0]=t0.h; h2[1]=t1.h; h2[2]=t2.h; h2[3]=t3.h; h2[4]=t4.h; h2[5]=t5.h; h2[6]=t6.h; h2[7]=t7.h; \
        l2[0]=t0.l; l2[1]=t1.l; l2[2]=t2.l; l2[3]=t3.l; l2[4]=t4.l; l2[5]=t5.l; l2[6]=t6.l; l2[7]=t7.l; \
        aQ_.h[1] = h2; aQ_.l[1] = l2;                                                          \
    }
#define DO_QK(dsth, dstl)                                             \
    {                                                                 \
        Frag aQ; BUILD_AQ(aQ)                                         \
        Frag bKM = ld_frag(KMh, KMl, brow, kg);                       \
        f32x4 q0 = mm16_rr(aQ, bKM, z4());                            \
        float qv[4];                                                  \
        _Pragma("unroll")                                             \
        for (int m = 0; m < 4; ++m) qv[m] = activ_f(q0[m]);           \
        wfrag_rm(dsth, dstl, Rb, C, qv);                              \
    }
#define DO_W(srch, srcl, dsth, dstl)                                  \
    {                                                                 \
        Frag aK = ld_frag(srch, srcl, arow, kg);                      \
        Frag bZt = ld_frag(Z0th, Z0tl, brow, kg);                     \
        f32x4 w0 = mm16_rr(aK, bZt, z4());                            \
        float wv2[4];                                                 \
        _Pragma("unroll")                                             \
        for (int m = 0; m < 4; ++m) wv2[m] = w0[m] * ZINV;            \
        wfrag_rm(dsth, dstl, Rb, C, wv2);                             \
    }
#define DO_PROD(srch, srcl, tt_)                                      \
    {                                                                 \
        Frag aW2 = ld_frag(srch, srcl, arow, kg);                     \
        Frag bKV = ld_frag(KVh, KVl, brow, kg);                       \
        f32x4 p0 = mm16_rr(aW2, bKV, z4());                           \
        Frag fk;                                                      \
        _Pragma("unroll")                                             \
        for (int s = 0; s < 2; ++s) {                                 \
            const int o = (s << 5) + (kg << 3);                       \
            fk.h[s] = *(const f16x8*)(kv1h + o);                      \
            fk.l[s] = *(const f16x8*)(kv1l + o);                      \
        }                                                             \
        f32x4 d4 = mm16_rr(aW2, fk, z4());                            \
        _Pragma("unroll")                                             \
        for (int m = 0; m < 4; ++m) {                                 \
            const int R = Rb + m;                                     \
            og[(size_t)(((tt_) << 6) + R) * 64 + C] = p0[m] / (d4[m] + 1e-12f); \
        }                                                             \
    }

    LOAD_Q(0)
    DO_QK(SCh, SCl)
    LOAD_Q(1)
    __syncthreads();
    DO_W(SCh, SCl, SBh, SBl)
    DO_QK(SAh, SAl)
    LOAD_Q(2)
    __syncthreads();
    DO_PROD(SBh, SBl, 0)
    DO_W(SAh, SAl, Xh, Xl)
    DO_QK(SCh, SCl)
    LOAD_Q(3)
    __syncthreads();
    DO_PROD(Xh, Xl, 1)
    DO_W(SCh, SCl, SBh, SBl)
    DO_QK(SAh, SAl)
    __syncthreads();
    DO_PROD(SBh, SBl, 2)
    DO_W(SAh, SAl, Xh, Xl)
    __syncthreads();
    DO_PROD(Xh, Xl, 3)
#undef LOAD_Q
#undef BUILD_AQ
#undef DO_QK
#undef DO_W
#undef DO_PROD
}

extern "C" void kernel_launch(void* const* d_in, const int* in_sizes, int n_in,
                              void* d_out, int out_size, void* d_ws, size_t ws_size,
                              hipStream_t stream) {
    const float* q = (const float*)d_in[0];
    const float* k = (const float*)d_in[1];
    const float* v = (const float*)d_in[2];
    float* out = (float*)d_out;
    float* ws  = (float*)d_ws;
    (void)in_sizes; (void)n_in; (void)out_size; (void)ws_size;

    hipFuncSetAttribute((const void*)k_main,
                        hipFuncAttributeMaxDynamicSharedMemorySize, SMEM_BYTES);

    k_init<<<1, 64, 0, stream>>>(ws);
    k_reduce<<<G_TOT, TPB_R, 0, stream>>>(q, k, ws);
    k_main<<<G_TOT, TPB_M, SMEM_BYTES, stream>>>(q, k, v, ws, out);
}